// Round 15
// baseline (250.056 us; speedup 1.0000x reference)
//
#include <hip/hip_runtime.h>
#include <hip/hip_bf16.h>

typedef short short8 __attribute__((ext_vector_type(8)));
typedef float f32x4 __attribute__((ext_vector_type(4)));

#define DIM 2048
#define NH 16
#define KV_RANK 512
#define Q_RANK 1536
#define ROPE_D 64
#define NOPE 128
#define VD 128
#define TT 2048
#define QKH 192                   // NOPE + ROPE
#define QD (NH * QKH)             // 3072
#define KVUP_D (NH * (NOPE + VD)) // 4096
#define WDN 2176                  // padded combined down-proj N (1536 + 576 + 64 pad)

__device__ inline unsigned short f2bf(float f) {
  __hip_bfloat16 h = __float2bfloat16(f);
  union { __hip_bfloat16 h; unsigned short u; } cv; cv.h = h; return cv.u;
}
__device__ inline float bf2f(unsigned short u) {
  union { unsigned int i; float f; } cv; cv.i = ((unsigned int)u) << 16; return cv.f;
}
__device__ inline void gload_lds16(const void* g, void* l) {
  __builtin_amdgcn_global_load_lds(
      (const __attribute__((address_space(1))) void*)g,
      (__attribute__((address_space(3))) void*)l, 16, 0, 0);
}

// ---------------- all fp32 -> bf16 converts in one launch ----------------
__global__ __launch_bounds__(256) void convert_all(
    const float* __restrict__ x, const float* __restrict__ wqd,
    const float* __restrict__ wkvd, const float* __restrict__ wqu,
    const float* __restrict__ wkvu, const float* __restrict__ wo,
    unsigned short* __restrict__ xb, unsigned short* __restrict__ wdb,
    unsigned short* __restrict__ wqub, unsigned short* __restrict__ wkvub,
    unsigned short* __restrict__ wob) {
  int i = blockIdx.x * 256 + threadIdx.x;
  const int n0 = TT * DIM / 4;
  const int n1 = WDN * 2048 / 4;
  const int n2 = QD * Q_RANK / 4;
  const int n3 = KVUP_D * KV_RANK / 4;
  const int n4 = DIM * DIM / 4;
  float4 v;
  unsigned short* dst;
  if (i < n0) { v = reinterpret_cast<const float4*>(x)[i]; dst = xb; }
  else if ((i -= n0) < n1) {
    int row = i >> 9, c4 = i & 511;   // 512 float4 per 2048-col row
    if (row < 1536)      v = reinterpret_cast<const float4*>(wqd)[row * 512 + c4];
    else if (row < 2112) v = reinterpret_cast<const float4*>(wkvd)[(row - 1536) * 512 + c4];
    else                 v = make_float4(0.f, 0.f, 0.f, 0.f);
    dst = wdb;
  }
  else if ((i -= n1) < n2) { v = reinterpret_cast<const float4*>(wqu)[i]; dst = wqub; }
  else if ((i -= n2) < n3) { v = reinterpret_cast<const float4*>(wkvu)[i]; dst = wkvub; }
  else if ((i -= n3) < n4) { v = reinterpret_cast<const float4*>(wo)[i]; dst = wob; }
  else return;
  ushort4 o;
  o.x = f2bf(v.x); o.y = f2bf(v.y); o.z = f2bf(v.z); o.w = f2bf(v.w);
  reinterpret_cast<ushort4*>(dst)[i] = o;
}

// ------- single-buffered m97-style core, 128M x 128N (for gemm_dual) -------
__device__ __forceinline__ void gemm_core_sb(const unsigned short* __restrict__ A,
                                             const unsigned short* __restrict__ W,
                                             unsigned short* As, unsigned short* Bs,
                                             int K, int lda, int ldb,
                                             int bm, int bn, int tid,
                                             f32x4 (&acc)[4][4]) {
  const int lane = tid & 63, wave = tid >> 6;
  const int wm = (wave >> 1) * 64, wn = (wave & 1) * 64;
  const int fr = lane & 15, fg = lane >> 4;
  const int sr = lane >> 3, scb = (lane & 7) ^ sr;
  const int r0 = wave * 32;

  const unsigned short* Ag = A + (size_t)(bm + r0 + sr) * lda + scb * 8;
  const unsigned short* Wg = W + (size_t)(bn + r0 + sr) * ldb + scb * 8;

  for (int k0 = 0; k0 < K; k0 += 64) {
#pragma unroll
    for (int i = 0; i < 4; ++i) {
      gload_lds16(Ag + k0 + (size_t)(i * 8) * lda, As + r0 * 64 + i * 512);
      gload_lds16(Wg + k0 + (size_t)(i * 8) * ldb, Bs + r0 * 64 + i * 512);
    }
    __syncthreads();
    __builtin_amdgcn_s_setprio(1);
#pragma unroll
    for (int kk = 0; kk < 2; ++kk) {
      short8 a[4], b[4];
#pragma unroll
      for (int i = 0; i < 4; ++i) {
        int ra = wm + i * 16 + fr;
        a[i] = *reinterpret_cast<const short8*>(&As[ra * 64 + (((kk * 4 + fg) ^ (ra & 7)) * 8)]);
        int rb = wn + i * 16 + fr;
        b[i] = *reinterpret_cast<const short8*>(&Bs[rb * 64 + (((kk * 4 + fg) ^ (rb & 7)) * 8)]);
      }
#pragma unroll
      for (int i = 0; i < 4; ++i)
#pragma unroll
        for (int j = 0; j < 4; ++j)
          acc[i][j] = __builtin_amdgcn_mfma_f32_16x16x32_bf16(a[i], b[j], acc[i][j], 0, 0, 0);
    }
    __builtin_amdgcn_s_setprio(0);
    __syncthreads();
  }
}

// ------- 64M x 128N single-buffered GEMM (2+ blocks/CU for ~1-block/CU grids) --
__global__ __launch_bounds__(256) void gemm_m64(const unsigned short* __restrict__ A,
                                                const unsigned short* __restrict__ W,
                                                float* __restrict__ Cf,
                                                unsigned short* __restrict__ Cb,
                                                int K, int lda, int ldb, int ldc) {
  __shared__ __align__(16) unsigned short As[64 * 64];    // 8KB
  __shared__ __align__(16) unsigned short Bs[128 * 64];   // 16KB
  const int tid = threadIdx.x;
  const int bm = blockIdx.y * 64, bn = blockIdx.x * 128;
  const int lane = tid & 63, wave = tid >> 6;
  const int wm = (wave >> 1) * 32, wn = (wave & 1) * 64;
  const int fr = lane & 15, fg = lane >> 4;

  f32x4 acc[2][4] = {};

  for (int k0 = 0; k0 < K; k0 += 64) {
#pragma unroll
    for (int i = 0; i < 2; ++i) {
      int u = tid + i * 256;
      int row = u >> 3, cb = u & 7;
      gload_lds16(A + (size_t)(bm + row) * lda + k0 + ((cb ^ (row & 7)) * 8), As + u * 8);
    }
#pragma unroll
    for (int i = 0; i < 4; ++i) {
      int u = tid + i * 256;
      int row = u >> 3, cb = u & 7;
      gload_lds16(W + (size_t)(bn + row) * ldb + k0 + ((cb ^ (row & 7)) * 8), Bs + u * 8);
    }
    __syncthreads();
    __builtin_amdgcn_s_setprio(1);
#pragma unroll
    for (int kk = 0; kk < 2; ++kk) {
      short8 a[2], b[4];
#pragma unroll
      for (int i = 0; i < 2; ++i) {
        int ra = wm + i * 16 + fr;
        a[i] = *reinterpret_cast<const short8*>(&As[ra * 64 + (((kk * 4 + fg) ^ (ra & 7)) * 8)]);
      }
#pragma unroll
      for (int j = 0; j < 4; ++j) {
        int rb = wn + j * 16 + fr;
        b[j] = *reinterpret_cast<const short8*>(&Bs[rb * 64 + (((kk * 4 + fg) ^ (rb & 7)) * 8)]);
      }
#pragma unroll
      for (int i = 0; i < 2; ++i)
#pragma unroll
        for (int j = 0; j < 4; ++j)
          acc[i][j] = __builtin_amdgcn_mfma_f32_16x16x32_bf16(a[i], b[j], acc[i][j], 0, 0, 0);
    }
    __builtin_amdgcn_s_setprio(0);
    __syncthreads();
  }

  if (Cb) {
#pragma unroll
    for (int i = 0; i < 2; ++i) {
      int row0 = bm + wm + i * 16 + fg * 4;
#pragma unroll
      for (int j = 0; j < 4; ++j) {
        int col = bn + wn + j * 16 + fr;
#pragma unroll
        for (int r = 0; r < 4; ++r)
          Cb[(size_t)(row0 + r) * ldc + col] = f2bf(acc[i][j][r]);
      }
    }
  } else {
#pragma unroll
    for (int i = 0; i < 2; ++i) {
      int row0 = bm + wm + i * 16 + fg * 4;
#pragma unroll
      for (int j = 0; j < 4; ++j) {
        int col = bn + wn + j * 16 + fr;
#pragma unroll
        for (int r = 0; r < 4; ++r)
          Cf[(size_t)(row0 + r) * ldc + col] = acc[i][j][r];
      }
    }
  }
}

// ------- dual GEMM (single-buf core): bx<384 qup -> C1; else kvup -> kbuf+vtb --
__global__ __launch_bounds__(256) void gemm_dual(
    const unsigned short* __restrict__ A1, const unsigned short* __restrict__ W1,
    unsigned short* __restrict__ C1,
    const unsigned short* __restrict__ A2, const unsigned short* __restrict__ W2,
    unsigned short* __restrict__ kbuf, unsigned short* __restrict__ vt) {
  __shared__ __align__(16) unsigned short As[128 * 64];
  __shared__ __align__(16) unsigned short Bs[128 * 64];
  const int tid = threadIdx.x;
  const int s = blockIdx.x;
  const unsigned short *A, *W;
  int K, lda, bm, bn;
  const bool isq = (s < 384);
  if (isq) {
    A = A1; W = W1; K = Q_RANK; lda = Q_RANK;
    bn = (s % 24) * 128; bm = (s / 24) * 128;
  } else {
    int b2 = s - 384;
    A = A2; W = W2; K = KV_RANK; lda = KV_RANK;
    bn = (b2 & 31) * 128; bm = (b2 >> 5) * 128;
  }
  const int lane = tid & 63, wave = tid >> 6;
  const int wm = (wave >> 1) * 64, wn = (wave & 1) * 64;
  const int fr = lane & 15, fg = lane >> 4;

  f32x4 acc[4][4] = {};
  gemm_core_sb(A, W, As, Bs, K, lda, lda, bm, bn, tid, acc);

  if (isq) {
#pragma unroll
    for (int i = 0; i < 4; ++i) {
      int row0 = bm + wm + i * 16 + fg * 4;
#pragma unroll
      for (int j = 0; j < 4; ++j) {
        int col = bn + wn + j * 16 + fr;
#pragma unroll
        for (int r = 0; r < 4; ++r)
          C1[(size_t)(row0 + r) * QD + col] = f2bf(acc[i][j][r]);
      }
    }
  } else {
    // kvup: cols [h*256, h*256+128) = k_nope -> kbuf[h][t][c]; [128,256) = v -> vt
#pragma unroll
    for (int i = 0; i < 4; ++i) {
      int row0 = bm + wm + i * 16 + fg * 4;
#pragma unroll
      for (int j = 0; j < 4; ++j) {
        int col = bn + wn + j * 16 + fr;
        int hh = col >> 8, cc = col & 255;
        if (cc < 128) {
#pragma unroll
          for (int r = 0; r < 4; ++r)
            kbuf[((size_t)hh * TT + row0 + r) * QKH + cc] = f2bf(acc[i][j][r]);
        } else {
          ushort4 w4;
          w4.x = f2bf(acc[i][j][0]); w4.y = f2bf(acc[i][j][1]);
          w4.z = f2bf(acc[i][j][2]); w4.w = f2bf(acc[i][j][3]);
          *reinterpret_cast<ushort4*>(vt + (size_t)(hh * VD + cc - 128) * TT + row0) = w4;
        }
      }
    }
  }
}

// ------- merged RMSNorm: per row, q-norm (1536) + kv-norm (512) -------
__global__ __launch_bounds__(256) void rmsnorm_both(
    const unsigned short* __restrict__ cqkv,
    const float* __restrict__ qw, const float* __restrict__ kvw,
    unsigned short* __restrict__ cq, unsigned short* __restrict__ ckv) {
  const int row = blockIdx.x, tid = threadIdx.x;
  __shared__ float red[256];
  const unsigned short* base = cqkv + (size_t)row * WDN;

#pragma unroll
  for (int ph = 0; ph < 2; ++ph) {
    const int cols = ph ? KV_RANK : Q_RANK;
    const int nch = cols >> 3;
    const unsigned short* x = base + (ph ? Q_RANK : 0);
    const float* w = ph ? kvw : qw;
    unsigned short* out = (ph ? ckv : cq) + (size_t)row * cols;
    float ss = 0.f;
    for (int cb = tid; cb < nch; cb += 256) {
      short8 v = *reinterpret_cast<const short8*>(x + cb * 8);
#pragma unroll
      for (int e = 0; e < 8; ++e) { float f = bf2f((unsigned short)v[e]); ss += f * f; }
    }
    red[tid] = ss; __syncthreads();
    for (int off = 128; off > 0; off >>= 1) {
      if (tid < off) red[tid] += red[tid + off];
      __syncthreads();
    }
    float r = rsqrtf(red[0] / (float)cols + 1e-6f);
    __syncthreads();
    for (int cb = tid; cb < nch; cb += 256) {
      short8 v = *reinterpret_cast<const short8*>(x + cb * 8);
      ushort4 o0, o1;
      o0.x = f2bf(bf2f((unsigned short)v[0]) * r * w[cb * 8 + 0]);
      o0.y = f2bf(bf2f((unsigned short)v[1]) * r * w[cb * 8 + 1]);
      o0.z = f2bf(bf2f((unsigned short)v[2]) * r * w[cb * 8 + 2]);
      o0.w = f2bf(bf2f((unsigned short)v[3]) * r * w[cb * 8 + 3]);
      o1.x = f2bf(bf2f((unsigned short)v[4]) * r * w[cb * 8 + 4]);
      o1.y = f2bf(bf2f((unsigned short)v[5]) * r * w[cb * 8 + 5]);
      o1.z = f2bf(bf2f((unsigned short)v[6]) * r * w[cb * 8 + 6]);
      o1.w = f2bf(bf2f((unsigned short)v[7]) * r * w[cb * 8 + 7]);
      *reinterpret_cast<ushort4*>(out + cb * 8) = o0;
      *reinterpret_cast<ushort4*>(out + cb * 8 + 4) = o1;
    }
  }
}

// ------- RoPE in-place on bf16 q rows + k_rope into kbuf (all heads) -------
__global__ __launch_bounds__(256) void rope_kernel(unsigned short* __restrict__ qb,
                                                   const unsigned short* __restrict__ cqkv,
                                                   unsigned short* __restrict__ kbuf) {
  const int t = blockIdx.x, tid = threadIdx.x;
  unsigned short* qrow = qb + (size_t)t * QD;
  for (int p = tid; p < NH * 32 + 32; p += 256) {
    int j = (p < NH * 32) ? (p & 31) : (p - NH * 32);
    float inv = powf(500000.0f, -(float)(2 * j) * (1.0f / 64.0f));
    float ang = (float)t * inv;
    float sv, cv;
    sincosf(ang, &sv, &cv);
    if (p < NH * 32) {
      int h = p >> 5;
      unsigned short* b = qrow + h * QKH + NOPE + 2 * j;
      float e = bf2f(b[0]), o = bf2f(b[1]);
      b[0] = f2bf(e * cv - o * sv);
      b[1] = f2bf(o * cv + e * sv);
    } else {
      const unsigned short* b = cqkv + (size_t)t * WDN + 2048 + 2 * j;
      float e = bf2f(b[0]), o = bf2f(b[1]);
      unsigned short re = f2bf(e * cv - o * sv);
      unsigned short ro = f2bf(o * cv + e * sv);
#pragma unroll
      for (int hh = 0; hh < NH; ++hh) {
        kbuf[((size_t)hh * TT + t) * QKH + NOPE + 2 * j]     = re;
        kbuf[((size_t)hh * TT + t) * QKH + NOPE + 2 * j + 1] = ro;
      }
    }
  }
}

// ---- k-split MFMA flash attn: 49KB LDS -> 3 blocks/CU; Ps per-wave stride-72 ----
// 640 blocks: b -> h = b&15, w = b>>4 (big q-tiles first). qt 0..15 (128 q-rows),
// chunk c covers 64-key k-tiles [8c, min(8c+8, 2qt+2)).
__global__ __launch_bounds__(256, 3) void attn_part(
    const unsigned short* __restrict__ qb,    // [T][3072] (rope applied)
    const unsigned short* __restrict__ kbuf,  // [H][T][192]
    const unsigned short* __restrict__ vtb,   // [H*128][T]
    unsigned short* __restrict__ Opart,       // [1024 slots][128][128] bf16
    float* __restrict__ ml)                   // [1024 slots][128][2]
{
  const int b = blockIdx.x;
  const int h = b & 15;
  const int w = b >> 4;
  int qt, c;
  if (w < 16)      { qt = 15 - (w >> 2); c = w & 3; }
  else if (w < 28) { int v = w - 16; qt = 11 - v / 3; c = v % 3; }
  else if (w < 36) { qt = 7 - ((w - 28) >> 1); c = (w - 28) & 1; }
  else             { qt = 3 - (w - 36); c = 0; }
  const int t0 = qt * 128;
  const int ktlo = c * 8;
  const int kthi = min(c * 8 + 8, 2 * qt + 2);
  const int tid = threadIdx.x;
  const int lane = tid & 63, wv = tid >> 6;
  const int fr = lane & 15, fg = lane >> 4;

  __shared__ __align__(16) unsigned short KVl[2560 * 8];  // K 1536u + V 1024u = 40KB
  __shared__ __align__(16) unsigned short Ps[4][16 * 72]; // 9KB, per-wave, s-sequential
  unsigned short* Kl = KVl;             // [64][192] + XOR
  unsigned short* Vt = KVl + 12288;     // [128][64] + XOR

  short8 qf[2][6];
#pragma unroll
  for (int s = 0; s < 2; ++s) {
    const unsigned short* qrow = qb + (size_t)(t0 + wv * 32 + s * 16 + fr) * QD + h * QKH;
#pragma unroll
    for (int kc = 0; kc < 6; ++kc)
      qf[s][kc] = *reinterpret_cast<const short8*>(qrow + kc * 32 + fg * 8);
  }
  asm volatile("s_waitcnt vmcnt(0)" ::: "memory");  // drain Q so loop vmcnt counts are exact

  f32x4 o[2][8] = {};
  float m2[2] = {-1e30f, -1e30f};
  float l2[2] = {0.f, 0.f};
  const float scale = 0.0721687836487032f;  // 1/sqrt(192)
  const unsigned short* kb = kbuf + (size_t)h * TT * QKH;
  const unsigned short* vb = vtb + (size_t)h * VD * TT;

  for (int kt = ktlo; kt < kthi; ++kt) {
    const int kt0 = kt * 64;
    // stage K (6 gloads/thread), then V (4 gloads/thread)
#pragma unroll
    for (int i = 0; i < 6; ++i) {
      int u = tid + i * 256;
      int row = u / 24, cb = u - (u / 24) * 24;
      int cbs = cb ^ (row & 7);
      gload_lds16(kb + (size_t)(kt0 + row) * QKH + cbs * 8, Kl + u * 8);
    }
#pragma unroll
    for (int i = 0; i < 4; ++i) {
      int u = tid + i * 256;
      int d = u >> 3, cb = u & 7;
      int cbs = cb ^ (d & 7);
      gload_lds16(vb + (size_t)d * TT + kt0 + cbs * 8, Vt + u * 8);
    }
    asm volatile("s_waitcnt vmcnt(4)" ::: "memory");  // K landed; V's 4 still in flight
    __builtin_amdgcn_s_barrier();
    asm volatile("" ::: "memory");

    // S^T = K Q for both q-subtiles (single K pass)
    f32x4 sA[2][4] = {};
    __builtin_amdgcn_s_setprio(1);
#pragma unroll
    for (int kc = 0; kc < 6; ++kc) {
#pragma unroll
      for (int kr = 0; kr < 4; ++kr) {
        int row = kr * 16 + fr;
        short8 kf = *reinterpret_cast<const short8*>(
            &Kl[row * QKH + (((kc * 4 + fg) ^ (row & 7)) * 8)]);
        sA[0][kr] = __builtin_amdgcn_mfma_f32_16x16x32_bf16(kf, qf[0][kc], sA[0][kr], 0, 0, 0);
        sA[1][kr] = __builtin_amdgcn_mfma_f32_16x16x32_bf16(kf, qf[1][kc], sA[1][kr], 0, 0, 0);
      }
    }
    __builtin_amdgcn_s_setprio(0);

    const bool diag = (kt0 + 64 > t0);
    bool vwaited = false;
#pragma unroll
    for (int s = 0; s < 2; ++s) {
      const int qg = t0 + wv * 32 + s * 16 + fr;
      float mx = -1e30f;
#pragma unroll
      for (int kr = 0; kr < 4; ++kr)
#pragma unroll
        for (int r = 0; r < 4; ++r) {
          float svv = sA[s][kr][r] * scale;
          if (diag && (kt0 + kr * 16 + fg * 4 + r) > qg) svv = -1e30f;
          sA[s][kr][r] = svv;
          mx = fmaxf(mx, svv);
        }
      mx = fmaxf(mx, __shfl_xor(mx, 16));
      mx = fmaxf(mx, __shfl_xor(mx, 32));
      float mn = fmaxf(m2[s], mx);
      float corr = __expf(m2[s] - mn);
      m2[s] = mn;
      float ssum = 0.f;
#pragma unroll
      for (int kr = 0; kr < 4; ++kr) {
        ushort4 pk;
        float p0 = __expf(sA[s][kr][0] - mn);
        float p1 = __expf(sA[s][kr][1] - mn);
        float p2 = __expf(sA[s][kr][2] - mn);
        float p3 = __expf(sA[s][kr][3] - mn);
        ssum += p0 + p1 + p2 + p3;
        pk.x = f2bf(p0); pk.y = f2bf(p1); pk.z = f2bf(p2); pk.w = f2bf(p3);
        // P[q=fr][k = kr*16 + fg*4 + r], linear stride-72 row
        *reinterpret_cast<ushort4*>(&Ps[wv][fr * 72 + kr * 16 + fg * 4]) = pk;
      }
      ssum += __shfl_xor(ssum, 16);
      ssum += __shfl_xor(ssum, 32);
      l2[s] = l2[s] * corr + ssum;
      if (__any(corr != 1.0f)) {
        float c0 = __shfl(corr, fg * 4 + 0);
        float c1 = __shfl(corr, fg * 4 + 1);
        float c2 = __shfl(corr, fg * 4 + 2);
        float c3 = __shfl(corr, fg * 4 + 3);
#pragma unroll
        for (int dj = 0; dj < 8; ++dj) {
          o[s][dj][0] *= c0; o[s][dj][1] *= c1;
          o[s][dj][2] *= c2; o[s][dj][3] *= c3;
        }
      }

      if (!vwaited) {  // first PV needs V: drain remaining gloads + block barrier
        asm volatile("s_waitcnt vmcnt(0)" ::: "memory");
        __builtin_amdgcn_s_barrier();
        asm volatile("" ::: "memory");
        vwaited = true;
      }
      // O[s] += P V  (Ps buffer reused across s; within-wave write->read)
      __builtin_amdgcn_s_setprio(1);
#pragma unroll
      for (int kk = 0; kk < 2; ++kk) {
        short8 pa = *reinterpret_cast<const short8*>(&Ps[wv][fr * 72 + kk * 32 + fg * 8]);
#pragma unroll
        for (int dj = 0; dj < 8; ++dj) {
          int dv = dj * 16 + fr;
          short8 bv = *reinterpret_cast<const short8*>(
              &Vt[dv * 64 + (((kk * 4 + fg) ^ (dv & 7)) * 8)]);
          o[s][dj] = __builtin_amdgcn_mfma_f32_16x16x32_bf16(pa, bv, o[s][dj], 0, 0, 0);
        }
      }
      __builtin_amdgcn_s_setprio(0);
    }
    asm volatile("" ::: "memory");
    __builtin_amdgcn_s_barrier();   // protect Kl/Vt before next-iter staging
  }

  const int slot = (h * 16 + qt) * 4 + c;
#pragma unroll
  for (int s = 0; s < 2; ++s) {
#pragma unroll
    for (int r = 0; r < 4; ++r) {
      int row = wv * 32 + s * 16 + fg * 4 + r;
      unsigned short* orow = Opart + ((size_t)slot * 128 + row) * 128;
#pragma unroll
      for (int dj = 0; dj < 8; ++dj)
        orow[dj * 16 + fr] = f2bf(o[s][dj][r]);
    }
    if (fg == 0) {
      int row = wv * 32 + s * 16 + fr;
      ml[((size_t)slot * 128 + row) * 2]     = m2[s];
      ml[((size_t)slot * 128 + row) * 2 + 1] = l2[s];
    }
  }
}

// ---------------- combine partials -> attn output (bf16) ----------------
__global__ __launch_bounds__(256) void attn_combine(
    const unsigned short* __restrict__ Opart, const float* __restrict__ ml,
    unsigned short* __restrict__ out) {
  const int bid = blockIdx.x;          // h*32 + qt*2 + rowhalf
  const int h = bid >> 5;
  const int qt = (bid >> 1) & 15;
  const int rh = bid & 1;
  const int nch = qt / 4 + 1;
  const int tid = threadIdx.x;
  const int row = rh * 64 + (tid >> 2), dg = tid & 3;
  const int base = (h * 16 + qt) * 4;
  float mm[4], ll[4];
  float M = -1e30f;
#pragma unroll
  for (int cc = 0; cc < 4; ++cc) {
    if (cc < nch) {
      mm[cc] = ml[((size_t)(base + cc) * 128 + row) * 2];
      ll[cc] = ml[((size_t)(base + cc) * 128 + row) * 2 + 1];
      M = fmaxf(M, mm[cc]);
    } else { mm[cc] = -1e30f; ll[cc] = 0.f; }
  }
  float L = 0.f;
#pragma unroll
  for (int cc = 0; cc < 4; ++cc) {
    mm[cc] = __expf(mm[cc] - M);
    L += ll[cc] * mm[cc];
  }
  float acc[32] = {};
#pragma unroll
  for (int cc = 0; cc < 4; ++cc) {
    if (cc < nch) {
      const unsigned short* op = Opart + ((size_t)(base + cc) * 128 + row) * 128 + dg * 32;
      float sc = mm[cc];
#pragma unroll
      for (int e8 = 0; e8 < 4; ++e8) {
        short8 v = *reinterpret_cast<const short8*>(op + e8 * 8);
#pragma unroll
        for (int e = 0; e < 8; ++e) acc[e8 * 8 + e] += bf2f((unsigned short)v[e]) * sc;
      }
    }
  }
  float linv = 1.0f / L;
  unsigned short* dst = out + (size_t)(qt * 128 + row) * DIM + h * VD + dg * 32;
#pragma unroll
  for (int e4 = 0; e4 < 8; ++e4) {
    ushort4 w4;
    w4.x = f2bf(acc[e4 * 4 + 0] * linv);
    w4.y = f2bf(acc[e4 * 4 + 1] * linv);
    w4.z = f2bf(acc[e4 * 4 + 2] * linv);
    w4.w = f2bf(acc[e4 * 4 + 3] * linv);
    *reinterpret_cast<ushort4*>(dst + e4 * 4) = w4;
  }
}

// ---------------- launch ----------------
extern "C" void kernel_launch(void* const* d_in, const int* in_sizes, int n_in,
                              void* d_out, int out_size, void* d_ws, size_t ws_size,
                              hipStream_t stream) {
  const float* x        = (const float*)d_in[0];
  const float* w_q_down = (const float*)d_in[1];
  const float* q_norm_w = (const float*)d_in[2];
  const float* w_q_up   = (const float*)d_in[3];
  const float* w_kv_down= (const float*)d_in[4];
  const float* kv_norm_w= (const float*)d_in[5];
  const float* w_kv_up  = (const float*)d_in[6];
  const float* w_o      = (const float*)d_in[7];
  float* outp = (float*)d_out;

  char* ws = (char*)d_ws;
  size_t off = 0;
  auto alloc = [&](size_t bytes) {
    void* p = ws + off;
    off += (bytes + 255) & ~(size_t)255;
    return p;
  };
  unsigned short* x_bf     = (unsigned short*)alloc((size_t)TT * DIM * 2);   // reused: attn_bf
  unsigned short* wdown_bf = (unsigned short*)alloc((size_t)WDN * DIM * 2);
  unsigned short* wqu_bf   = (unsigned short*)alloc((size_t)QD * Q_RANK * 2);
  unsigned short* wkvu_bf  = (unsigned short*)alloc((size_t)KVUP_D * KV_RANK * 2);
  unsigned short* wo_bf    = (unsigned short*)alloc((size_t)DIM * DIM * 2);
  unsigned short* cqkv_bf  = (unsigned short*)alloc((size_t)TT * WDN * 2);
  unsigned short* cq_bf    = (unsigned short*)alloc((size_t)TT * Q_RANK * 2);
  unsigned short* ckv_bf   = (unsigned short*)alloc((size_t)TT * KV_RANK * 2);
  unsigned short* qb_bf    = (unsigned short*)alloc((size_t)TT * QD * 2);
  unsigned short* kbuf     = (unsigned short*)alloc((size_t)NH * TT * QKH * 2);
  unsigned short* vtb      = (unsigned short*)alloc((size_t)NH * VD * TT * 2);
  unsigned short* Opart    = (unsigned short*)alloc((size_t)1024 * 128 * 128 * 2);
  float*          mlbuf    = (float*)alloc((size_t)1024 * 128 * 2 * 4);
  unsigned short* attn_bf  = x_bf;  // x_bf dead after down-GEMM

  {
    int total = TT * DIM / 4 + WDN * 2048 / 4 + QD * Q_RANK / 4 +
                KVUP_D * KV_RANK / 4 + DIM * DIM / 4;
    convert_all<<<dim3((total + 255) / 256), dim3(256), 0, stream>>>(
        x, w_q_down, w_kv_down, w_q_up, w_kv_up, w_o,
        x_bf, wdown_bf, wqu_bf, wkvu_bf, wo_bf);
  }

  dim3 blk(256);
  // combined down-proj: cqkv = x @ [w_q_down; w_kv_down; pad]^T  [2048 x 2176]
  gemm_m64<<<dim3(WDN / 128, TT / 64), blk, 0, stream>>>(
      x_bf, wdown_bf, nullptr, cqkv_bf, DIM, DIM, DIM, WDN);
  rmsnorm_both<<<dim3(TT), blk, 0, stream>>>(cqkv_bf, q_norm_w, kv_norm_w, cq_bf, ckv_bf);
  // qup -> qb ; kvup -> kbuf (k_nope) + vtb (V^T), one dispatch (single-buf core)
  gemm_dual<<<dim3(896), blk, 0, stream>>>(cq_bf, wqu_bf, qb_bf,
                                           ckv_bf, wkvu_bf, kbuf, vtb);
  rope_kernel<<<dim3(TT), blk, 0, stream>>>(qb_bf, cqkv_bf, kbuf);
  attn_part<<<dim3(640), blk, 0, stream>>>(qb_bf, kbuf, vtb, Opart, mlbuf);
  attn_combine<<<dim3(512), blk, 0, stream>>>(Opart, mlbuf, attn_bf);
  // out = attn @ w_o^T  [2048 x 2048]
  gemm_m64<<<dim3(DIM / 128, TT / 64), blk, 0, stream>>>(
      attn_bf, wo_bf, outp, nullptr, DIM, DIM, DIM, DIM);
}

// Round 17
// 233.806 us; speedup vs baseline: 1.0695x; 1.0695x over previous
//
#include <hip/hip_runtime.h>
#include <hip/hip_bf16.h>

typedef short short8 __attribute__((ext_vector_type(8)));
typedef float f32x4 __attribute__((ext_vector_type(4)));

#define DIM 2048
#define NH 16
#define KV_RANK 512
#define Q_RANK 1536
#define ROPE_D 64
#define NOPE 128
#define VD 128
#define TT 2048
#define QKH 192                   // NOPE + ROPE
#define QD (NH * QKH)             // 3072
#define KVUP_D (NH * (NOPE + VD)) // 4096
#define WDN 2176                  // padded combined down-proj N (1536 + 576 + 64 pad)

__device__ inline unsigned short f2bf(float f) {
  __hip_bfloat16 h = __float2bfloat16(f);
  union { __hip_bfloat16 h; unsigned short u; } cv; cv.h = h; return cv.u;
}
__device__ inline float bf2f(unsigned short u) {
  union { unsigned int i; float f; } cv; cv.i = ((unsigned int)u) << 16; return cv.f;
}
__device__ inline void gload_lds16(const void* g, void* l) {
  __builtin_amdgcn_global_load_lds(
      (const __attribute__((address_space(1))) void*)g,
      (__attribute__((address_space(3))) void*)l, 16, 0, 0);
}

// ---------------- all fp32 -> bf16 converts in one launch ----------------
__global__ __launch_bounds__(256) void convert_all(
    const float* __restrict__ x, const float* __restrict__ wqd,
    const float* __restrict__ wkvd, const float* __restrict__ wqu,
    const float* __restrict__ wkvu, const float* __restrict__ wo,
    unsigned short* __restrict__ xb, unsigned short* __restrict__ wdb,
    unsigned short* __restrict__ wqub, unsigned short* __restrict__ wkvub,
    unsigned short* __restrict__ wob) {
  int i = blockIdx.x * 256 + threadIdx.x;
  const int n0 = TT * DIM / 4;
  const int n1 = WDN * 2048 / 4;
  const int n2 = QD * Q_RANK / 4;
  const int n3 = KVUP_D * KV_RANK / 4;
  const int n4 = DIM * DIM / 4;
  float4 v;
  unsigned short* dst;
  if (i < n0) { v = reinterpret_cast<const float4*>(x)[i]; dst = xb; }
  else if ((i -= n0) < n1) {
    int row = i >> 9, c4 = i & 511;   // 512 float4 per 2048-col row
    if (row < 1536)      v = reinterpret_cast<const float4*>(wqd)[row * 512 + c4];
    else if (row < 2112) v = reinterpret_cast<const float4*>(wkvd)[(row - 1536) * 512 + c4];
    else                 v = make_float4(0.f, 0.f, 0.f, 0.f);
    dst = wdb;
  }
  else if ((i -= n1) < n2) { v = reinterpret_cast<const float4*>(wqu)[i]; dst = wqub; }
  else if ((i -= n2) < n3) { v = reinterpret_cast<const float4*>(wkvu)[i]; dst = wkvub; }
  else if ((i -= n3) < n4) { v = reinterpret_cast<const float4*>(wo)[i]; dst = wob; }
  else return;
  ushort4 o;
  o.x = f2bf(v.x); o.y = f2bf(v.y); o.z = f2bf(v.z); o.w = f2bf(v.w);
  reinterpret_cast<ushort4*>(dst)[i] = o;
}

// ------- single-buffered m97-style core, 128M x 128N (for gemm_dual) -------
__device__ __forceinline__ void gemm_core_sb(const unsigned short* __restrict__ A,
                                             const unsigned short* __restrict__ W,
                                             unsigned short* As, unsigned short* Bs,
                                             int K, int lda, int ldb,
                                             int bm, int bn, int tid,
                                             f32x4 (&acc)[4][4]) {
  const int lane = tid & 63, wave = tid >> 6;
  const int wm = (wave >> 1) * 64, wn = (wave & 1) * 64;
  const int fr = lane & 15, fg = lane >> 4;
  const int sr = lane >> 3, scb = (lane & 7) ^ sr;
  const int r0 = wave * 32;

  const unsigned short* Ag = A + (size_t)(bm + r0 + sr) * lda + scb * 8;
  const unsigned short* Wg = W + (size_t)(bn + r0 + sr) * ldb + scb * 8;

  for (int k0 = 0; k0 < K; k0 += 64) {
#pragma unroll
    for (int i = 0; i < 4; ++i) {
      gload_lds16(Ag + k0 + (size_t)(i * 8) * lda, As + r0 * 64 + i * 512);
      gload_lds16(Wg + k0 + (size_t)(i * 8) * ldb, Bs + r0 * 64 + i * 512);
    }
    __syncthreads();
    __builtin_amdgcn_s_setprio(1);
#pragma unroll
    for (int kk = 0; kk < 2; ++kk) {
      short8 a[4], b[4];
#pragma unroll
      for (int i = 0; i < 4; ++i) {
        int ra = wm + i * 16 + fr;
        a[i] = *reinterpret_cast<const short8*>(&As[ra * 64 + (((kk * 4 + fg) ^ (ra & 7)) * 8)]);
        int rb = wn + i * 16 + fr;
        b[i] = *reinterpret_cast<const short8*>(&Bs[rb * 64 + (((kk * 4 + fg) ^ (rb & 7)) * 8)]);
      }
#pragma unroll
      for (int i = 0; i < 4; ++i)
#pragma unroll
        for (int j = 0; j < 4; ++j)
          acc[i][j] = __builtin_amdgcn_mfma_f32_16x16x32_bf16(a[i], b[j], acc[i][j], 0, 0, 0);
    }
    __builtin_amdgcn_s_setprio(0);
    __syncthreads();
  }
}

// ------- 64M x 128N single-buffered GEMM (2+ blocks/CU for ~1-block/CU grids) --
__global__ __launch_bounds__(256) void gemm_m64(const unsigned short* __restrict__ A,
                                                const unsigned short* __restrict__ W,
                                                float* __restrict__ Cf,
                                                unsigned short* __restrict__ Cb,
                                                int K, int lda, int ldb, int ldc) {
  __shared__ __align__(16) unsigned short As[64 * 64];    // 8KB
  __shared__ __align__(16) unsigned short Bs[128 * 64];   // 16KB
  const int tid = threadIdx.x;
  const int bm = blockIdx.y * 64, bn = blockIdx.x * 128;
  const int lane = tid & 63, wave = tid >> 6;
  const int wm = (wave >> 1) * 32, wn = (wave & 1) * 64;
  const int fr = lane & 15, fg = lane >> 4;

  f32x4 acc[2][4] = {};

  for (int k0 = 0; k0 < K; k0 += 64) {
#pragma unroll
    for (int i = 0; i < 2; ++i) {
      int u = tid + i * 256;
      int row = u >> 3, cb = u & 7;
      gload_lds16(A + (size_t)(bm + row) * lda + k0 + ((cb ^ (row & 7)) * 8), As + u * 8);
    }
#pragma unroll
    for (int i = 0; i < 4; ++i) {
      int u = tid + i * 256;
      int row = u >> 3, cb = u & 7;
      gload_lds16(W + (size_t)(bn + row) * ldb + k0 + ((cb ^ (row & 7)) * 8), Bs + u * 8);
    }
    __syncthreads();
    __builtin_amdgcn_s_setprio(1);
#pragma unroll
    for (int kk = 0; kk < 2; ++kk) {
      short8 a[2], b[4];
#pragma unroll
      for (int i = 0; i < 2; ++i) {
        int ra = wm + i * 16 + fr;
        a[i] = *reinterpret_cast<const short8*>(&As[ra * 64 + (((kk * 4 + fg) ^ (ra & 7)) * 8)]);
      }
#pragma unroll
      for (int j = 0; j < 4; ++j) {
        int rb = wn + j * 16 + fr;
        b[j] = *reinterpret_cast<const short8*>(&Bs[rb * 64 + (((kk * 4 + fg) ^ (rb & 7)) * 8)]);
      }
#pragma unroll
      for (int i = 0; i < 2; ++i)
#pragma unroll
        for (int j = 0; j < 4; ++j)
          acc[i][j] = __builtin_amdgcn_mfma_f32_16x16x32_bf16(a[i], b[j], acc[i][j], 0, 0, 0);
    }
    __builtin_amdgcn_s_setprio(0);
    __syncthreads();
  }

  if (Cb) {
#pragma unroll
    for (int i = 0; i < 2; ++i) {
      int row0 = bm + wm + i * 16 + fg * 4;
#pragma unroll
      for (int j = 0; j < 4; ++j) {
        int col = bn + wn + j * 16 + fr;
#pragma unroll
        for (int r = 0; r < 4; ++r)
          Cb[(size_t)(row0 + r) * ldc + col] = f2bf(acc[i][j][r]);
      }
    }
  } else {
#pragma unroll
    for (int i = 0; i < 2; ++i) {
      int row0 = bm + wm + i * 16 + fg * 4;
#pragma unroll
      for (int j = 0; j < 4; ++j) {
        int col = bn + wn + j * 16 + fr;
#pragma unroll
        for (int r = 0; r < 4; ++r)
          Cf[(size_t)(row0 + r) * ldc + col] = acc[i][j][r];
      }
    }
  }
}

// ------- dual GEMM (single-buf core): bx<384 qup -> C1; else kvup -> kbuf+vtb --
__global__ __launch_bounds__(256) void gemm_dual(
    const unsigned short* __restrict__ A1, const unsigned short* __restrict__ W1,
    unsigned short* __restrict__ C1,
    const unsigned short* __restrict__ A2, const unsigned short* __restrict__ W2,
    unsigned short* __restrict__ kbuf, unsigned short* __restrict__ vt) {
  __shared__ __align__(16) unsigned short As[128 * 64];
  __shared__ __align__(16) unsigned short Bs[128 * 64];
  const int tid = threadIdx.x;
  const int s = blockIdx.x;
  const unsigned short *A, *W;
  int K, lda, bm, bn;
  const bool isq = (s < 384);
  if (isq) {
    A = A1; W = W1; K = Q_RANK; lda = Q_RANK;
    bn = (s % 24) * 128; bm = (s / 24) * 128;
  } else {
    int b2 = s - 384;
    A = A2; W = W2; K = KV_RANK; lda = KV_RANK;
    bn = (b2 & 31) * 128; bm = (b2 >> 5) * 128;
  }
  const int lane = tid & 63, wave = tid >> 6;
  const int wm = (wave >> 1) * 64, wn = (wave & 1) * 64;
  const int fr = lane & 15, fg = lane >> 4;

  f32x4 acc[4][4] = {};
  gemm_core_sb(A, W, As, Bs, K, lda, lda, bm, bn, tid, acc);

  if (isq) {
#pragma unroll
    for (int i = 0; i < 4; ++i) {
      int row0 = bm + wm + i * 16 + fg * 4;
#pragma unroll
      for (int j = 0; j < 4; ++j) {
        int col = bn + wn + j * 16 + fr;
#pragma unroll
        for (int r = 0; r < 4; ++r)
          C1[(size_t)(row0 + r) * QD + col] = f2bf(acc[i][j][r]);
      }
    }
  } else {
    // kvup: cols [h*256, h*256+128) = k_nope -> kbuf[h][t][c]; [128,256) = v -> vt
#pragma unroll
    for (int i = 0; i < 4; ++i) {
      int row0 = bm + wm + i * 16 + fg * 4;
#pragma unroll
      for (int j = 0; j < 4; ++j) {
        int col = bn + wn + j * 16 + fr;
        int hh = col >> 8, cc = col & 255;
        if (cc < 128) {
#pragma unroll
          for (int r = 0; r < 4; ++r)
            kbuf[((size_t)hh * TT + row0 + r) * QKH + cc] = f2bf(acc[i][j][r]);
        } else {
          ushort4 w4;
          w4.x = f2bf(acc[i][j][0]); w4.y = f2bf(acc[i][j][1]);
          w4.z = f2bf(acc[i][j][2]); w4.w = f2bf(acc[i][j][3]);
          *reinterpret_cast<ushort4*>(vt + (size_t)(hh * VD + cc - 128) * TT + row0) = w4;
        }
      }
    }
  }
}

// ------- merged RMSNorm: per row, q-norm (1536) + kv-norm (512) -------
__global__ __launch_bounds__(256) void rmsnorm_both(
    const unsigned short* __restrict__ cqkv,
    const float* __restrict__ qw, const float* __restrict__ kvw,
    unsigned short* __restrict__ cq, unsigned short* __restrict__ ckv) {
  const int row = blockIdx.x, tid = threadIdx.x;
  __shared__ float red[256];
  const unsigned short* base = cqkv + (size_t)row * WDN;

#pragma unroll
  for (int ph = 0; ph < 2; ++ph) {
    const int cols = ph ? KV_RANK : Q_RANK;
    const int nch = cols >> 3;
    const unsigned short* x = base + (ph ? Q_RANK : 0);
    const float* w = ph ? kvw : qw;
    unsigned short* out = (ph ? ckv : cq) + (size_t)row * cols;
    float ss = 0.f;
    for (int cb = tid; cb < nch; cb += 256) {
      short8 v = *reinterpret_cast<const short8*>(x + cb * 8);
#pragma unroll
      for (int e = 0; e < 8; ++e) { float f = bf2f((unsigned short)v[e]); ss += f * f; }
    }
    red[tid] = ss; __syncthreads();
    for (int off = 128; off > 0; off >>= 1) {
      if (tid < off) red[tid] += red[tid + off];
      __syncthreads();
    }
    float r = rsqrtf(red[0] / (float)cols + 1e-6f);
    __syncthreads();
    for (int cb = tid; cb < nch; cb += 256) {
      short8 v = *reinterpret_cast<const short8*>(x + cb * 8);
      ushort4 o0, o1;
      o0.x = f2bf(bf2f((unsigned short)v[0]) * r * w[cb * 8 + 0]);
      o0.y = f2bf(bf2f((unsigned short)v[1]) * r * w[cb * 8 + 1]);
      o0.z = f2bf(bf2f((unsigned short)v[2]) * r * w[cb * 8 + 2]);
      o0.w = f2bf(bf2f((unsigned short)v[3]) * r * w[cb * 8 + 3]);
      o1.x = f2bf(bf2f((unsigned short)v[4]) * r * w[cb * 8 + 4]);
      o1.y = f2bf(bf2f((unsigned short)v[5]) * r * w[cb * 8 + 5]);
      o1.z = f2bf(bf2f((unsigned short)v[6]) * r * w[cb * 8 + 6]);
      o1.w = f2bf(bf2f((unsigned short)v[7]) * r * w[cb * 8 + 7]);
      *reinterpret_cast<ushort4*>(out + cb * 8) = o0;
      *reinterpret_cast<ushort4*>(out + cb * 8 + 4) = o1;
    }
  }
}

// ------- RoPE in-place on bf16 q rows + k_rope into kbuf (all heads) -------
__global__ __launch_bounds__(256) void rope_kernel(unsigned short* __restrict__ qb,
                                                   const unsigned short* __restrict__ cqkv,
                                                   unsigned short* __restrict__ kbuf) {
  const int t = blockIdx.x, tid = threadIdx.x;
  unsigned short* qrow = qb + (size_t)t * QD;
  for (int p = tid; p < NH * 32 + 32; p += 256) {
    int j = (p < NH * 32) ? (p & 31) : (p - NH * 32);
    float inv = powf(500000.0f, -(float)(2 * j) * (1.0f / 64.0f));
    float ang = (float)t * inv;
    float sv, cv;
    sincosf(ang, &sv, &cv);
    if (p < NH * 32) {
      int h = p >> 5;
      unsigned short* b = qrow + h * QKH + NOPE + 2 * j;
      float e = bf2f(b[0]), o = bf2f(b[1]);
      b[0] = f2bf(e * cv - o * sv);
      b[1] = f2bf(o * cv + e * sv);
    } else {
      const unsigned short* b = cqkv + (size_t)t * WDN + 2048 + 2 * j;
      float e = bf2f(b[0]), o = bf2f(b[1]);
      unsigned short re = f2bf(e * cv - o * sv);
      unsigned short ro = f2bf(o * cv + e * sv);
#pragma unroll
      for (int hh = 0; hh < NH; ++hh) {
        kbuf[((size_t)hh * TT + t) * QKH + NOPE + 2 * j]     = re;
        kbuf[((size_t)hh * TT + t) * QKH + NOPE + 2 * j + 1] = ro;
      }
    }
  }
}

// ---- k-split MFMA flash attn: sequential-PV, Ps[4][16*72] -> 49KB, no reg cap ----
// 640 blocks: b -> h = b&15, w = b>>4 (big q-tiles first). qt 0..15 (128 q-rows),
// chunk c covers 64-key k-tiles [8c, min(8c+8, 2qt+2)).
__global__ __launch_bounds__(256) void attn_part(
    const unsigned short* __restrict__ qb,    // [T][3072] (rope applied)
    const unsigned short* __restrict__ kbuf,  // [H][T][192]
    const unsigned short* __restrict__ vtb,   // [H*128][T]
    unsigned short* __restrict__ Opart,       // [1024 slots][128][128] bf16
    float* __restrict__ ml)                   // [1024 slots][128][2]
{
  const int b = blockIdx.x;
  const int h = b & 15;
  const int w = b >> 4;
  int qt, c;
  if (w < 16)      { qt = 15 - (w >> 2); c = w & 3; }
  else if (w < 28) { int v = w - 16; qt = 11 - v / 3; c = v % 3; }
  else if (w < 36) { qt = 7 - ((w - 28) >> 1); c = (w - 28) & 1; }
  else             { qt = 3 - (w - 36); c = 0; }
  const int t0 = qt * 128;
  const int ktlo = c * 8;
  const int kthi = min(c * 8 + 8, 2 * qt + 2);
  const int tid = threadIdx.x;
  const int lane = tid & 63, wv = tid >> 6;
  const int fr = lane & 15, fg = lane >> 4;

  __shared__ __align__(16) unsigned short KVl[2560 * 8];  // K 1536u + V 1024u = 40KB
  __shared__ __align__(16) unsigned short Ps[4][16 * 72]; // 9.2KB, per-wave, s-sequential
  unsigned short* Kl = KVl;             // [64][192] + XOR
  unsigned short* Vt = KVl + 12288;     // [128][64] + XOR

  short8 qf[2][6];
#pragma unroll
  for (int s = 0; s < 2; ++s) {
    const unsigned short* qrow = qb + (size_t)(t0 + wv * 32 + s * 16 + fr) * QD + h * QKH;
#pragma unroll
    for (int kc = 0; kc < 6; ++kc)
      qf[s][kc] = *reinterpret_cast<const short8*>(qrow + kc * 32 + fg * 8);
  }
  asm volatile("s_waitcnt vmcnt(0)" ::: "memory");  // drain Q so loop vmcnt counts are exact

  f32x4 o[2][8] = {};
  float m2[2] = {-1e30f, -1e30f};
  float l2[2] = {0.f, 0.f};
  const float scale = 0.0721687836487032f;  // 1/sqrt(192)
  const unsigned short* kb = kbuf + (size_t)h * TT * QKH;
  const unsigned short* vb = vtb + (size_t)h * VD * TT;

  for (int kt = ktlo; kt < kthi; ++kt) {
    const int kt0 = kt * 64;
    // stage K (6 gloads/thread), then V (4 gloads/thread)
#pragma unroll
    for (int i = 0; i < 6; ++i) {
      int u = tid + i * 256;
      int row = u / 24, cb = u - (u / 24) * 24;
      int cbs = cb ^ (row & 7);
      gload_lds16(kb + (size_t)(kt0 + row) * QKH + cbs * 8, Kl + u * 8);
    }
#pragma unroll
    for (int i = 0; i < 4; ++i) {
      int u = tid + i * 256;
      int d = u >> 3, cb = u & 7;
      int cbs = cb ^ (d & 7);
      gload_lds16(vb + (size_t)d * TT + kt0 + cbs * 8, Vt + u * 8);
    }
    asm volatile("s_waitcnt vmcnt(4)" ::: "memory");  // K landed; V's 4 still in flight
    __builtin_amdgcn_s_barrier();
    asm volatile("" ::: "memory");

    // S^T = K Q for both q-subtiles (single K pass)
    f32x4 sA[2][4] = {};
    __builtin_amdgcn_s_setprio(1);
#pragma unroll
    for (int kc = 0; kc < 6; ++kc) {
#pragma unroll
      for (int kr = 0; kr < 4; ++kr) {
        int row = kr * 16 + fr;
        short8 kf = *reinterpret_cast<const short8*>(
            &Kl[row * QKH + (((kc * 4 + fg) ^ (row & 7)) * 8)]);
        sA[0][kr] = __builtin_amdgcn_mfma_f32_16x16x32_bf16(kf, qf[0][kc], sA[0][kr], 0, 0, 0);
        sA[1][kr] = __builtin_amdgcn_mfma_f32_16x16x32_bf16(kf, qf[1][kc], sA[1][kr], 0, 0, 0);
      }
    }
    __builtin_amdgcn_s_setprio(0);

    const bool diag = (kt0 + 64 > t0);
    bool vwaited = false;
#pragma unroll
    for (int s = 0; s < 2; ++s) {
      const int qg = t0 + wv * 32 + s * 16 + fr;
      float mx = -1e30f;
#pragma unroll
      for (int kr = 0; kr < 4; ++kr)
#pragma unroll
        for (int r = 0; r < 4; ++r) {
          float svv = sA[s][kr][r] * scale;
          if (diag && (kt0 + kr * 16 + fg * 4 + r) > qg) svv = -1e30f;
          sA[s][kr][r] = svv;
          mx = fmaxf(mx, svv);
        }
      mx = fmaxf(mx, __shfl_xor(mx, 16));
      mx = fmaxf(mx, __shfl_xor(mx, 32));
      float mn = fmaxf(m2[s], mx);
      float corr = __expf(m2[s] - mn);
      m2[s] = mn;
      float ssum = 0.f;
#pragma unroll
      for (int kr = 0; kr < 4; ++kr) {
        ushort4 pk;
        float p0 = __expf(sA[s][kr][0] - mn);
        float p1 = __expf(sA[s][kr][1] - mn);
        float p2 = __expf(sA[s][kr][2] - mn);
        float p3 = __expf(sA[s][kr][3] - mn);
        ssum += p0 + p1 + p2 + p3;
        pk.x = f2bf(p0); pk.y = f2bf(p1); pk.z = f2bf(p2); pk.w = f2bf(p3);
        // P[q=fr][k = kr*16 + fg*4 + r], linear stride-72 row (16B-aligned, 64 slots)
        *reinterpret_cast<ushort4*>(&Ps[wv][fr * 72 + kr * 16 + fg * 4]) = pk;
      }
      ssum += __shfl_xor(ssum, 16);
      ssum += __shfl_xor(ssum, 32);
      l2[s] = l2[s] * corr + ssum;
      if (__any(corr != 1.0f)) {
        float c0 = __shfl(corr, fg * 4 + 0);
        float c1 = __shfl(corr, fg * 4 + 1);
        float c2 = __shfl(corr, fg * 4 + 2);
        float c3 = __shfl(corr, fg * 4 + 3);
#pragma unroll
        for (int dj = 0; dj < 8; ++dj) {
          o[s][dj][0] *= c0; o[s][dj][1] *= c1;
          o[s][dj][2] *= c2; o[s][dj][3] *= c3;
        }
      }

      if (!vwaited) {  // first PV needs V: drain remaining gloads + block barrier
        asm volatile("s_waitcnt vmcnt(0)" ::: "memory");
        __builtin_amdgcn_s_barrier();
        asm volatile("" ::: "memory");
        vwaited = true;
      }
      // O[s] += P V  (Ps buffer reused across s; within-wave write->read)
      __builtin_amdgcn_s_setprio(1);
#pragma unroll
      for (int kk = 0; kk < 2; ++kk) {
        short8 pa = *reinterpret_cast<const short8*>(&Ps[wv][fr * 72 + kk * 32 + fg * 8]);
#pragma unroll
        for (int dj = 0; dj < 8; ++dj) {
          int dv = dj * 16 + fr;
          short8 bv = *reinterpret_cast<const short8*>(
              &Vt[dv * 64 + (((kk * 4 + fg) ^ (dv & 7)) * 8)]);
          o[s][dj] = __builtin_amdgcn_mfma_f32_16x16x32_bf16(pa, bv, o[s][dj], 0, 0, 0);
        }
      }
      __builtin_amdgcn_s_setprio(0);
    }
    asm volatile("" ::: "memory");
    __builtin_amdgcn_s_barrier();   // protect Kl/Vt before next-iter staging
  }

  const int slot = (h * 16 + qt) * 4 + c;
#pragma unroll
  for (int s = 0; s < 2; ++s) {
#pragma unroll
    for (int r = 0; r < 4; ++r) {
      int row = wv * 32 + s * 16 + fg * 4 + r;
      unsigned short* orow = Opart + ((size_t)slot * 128 + row) * 128;
#pragma unroll
      for (int dj = 0; dj < 8; ++dj)
        orow[dj * 16 + fr] = f2bf(o[s][dj][r]);
    }
    if (fg == 0) {
      int row = wv * 32 + s * 16 + fr;
      ml[((size_t)slot * 128 + row) * 2]     = m2[s];
      ml[((size_t)slot * 128 + row) * 2 + 1] = l2[s];
    }
  }
}

// ---------------- combine partials -> attn output (bf16) ----------------
__global__ __launch_bounds__(256) void attn_combine(
    const unsigned short* __restrict__ Opart, const float* __restrict__ ml,
    unsigned short* __restrict__ out) {
  const int bid = blockIdx.x;          // h*32 + qt*2 + rowhalf
  const int h = bid >> 5;
  const int qt = (bid >> 1) & 15;
  const int rh = bid & 1;
  const int nch = qt / 4 + 1;
  const int tid = threadIdx.x;
  const int row = rh * 64 + (tid >> 2), dg = tid & 3;
  const int base = (h * 16 + qt) * 4;
  float mm[4], ll[4];
  float M = -1e30f;
#pragma unroll
  for (int cc = 0; cc < 4; ++cc) {
    if (cc < nch) {
      mm[cc] = ml[((size_t)(base + cc) * 128 + row) * 2];
      ll[cc] = ml[((size_t)(base + cc) * 128 + row) * 2 + 1];
      M = fmaxf(M, mm[cc]);
    } else { mm[cc] = -1e30f; ll[cc] = 0.f; }
  }
  float L = 0.f;
#pragma unroll
  for (int cc = 0; cc < 4; ++cc) {
    mm[cc] = __expf(mm[cc] - M);
    L += ll[cc] * mm[cc];
  }
  float acc[32] = {};
#pragma unroll
  for (int cc = 0; cc < 4; ++cc) {
    if (cc < nch) {
      const unsigned short* op = Opart + ((size_t)(base + cc) * 128 + row) * 128 + dg * 32;
      float sc = mm[cc];
#pragma unroll
      for (int e8 = 0; e8 < 4; ++e8) {
        short8 v = *reinterpret_cast<const short8*>(op + e8 * 8);
#pragma unroll
        for (int e = 0; e < 8; ++e) acc[e8 * 8 + e] += bf2f((unsigned short)v[e]) * sc;
      }
    }
  }
  float linv = 1.0f / L;
  unsigned short* dst = out + (size_t)(qt * 128 + row) * DIM + h * VD + dg * 32;
#pragma unroll
  for (int e4 = 0; e4 < 8; ++e4) {
    ushort4 w4;
    w4.x = f2bf(acc[e4 * 4 + 0] * linv);
    w4.y = f2bf(acc[e4 * 4 + 1] * linv);
    w4.z = f2bf(acc[e4 * 4 + 2] * linv);
    w4.w = f2bf(acc[e4 * 4 + 3] * linv);
    *reinterpret_cast<ushort4*>(dst + e4 * 4) = w4;
  }
}

// ---------------- launch ----------------
extern "C" void kernel_launch(void* const* d_in, const int* in_sizes, int n_in,
                              void* d_out, int out_size, void* d_ws, size_t ws_size,
                              hipStream_t stream) {
  const float* x        = (const float*)d_in[0];
  const float* w_q_down = (const float*)d_in[1];
  const float* q_norm_w = (const float*)d_in[2];
  const float* w_q_up   = (const float*)d_in[3];
  const float* w_kv_down= (const float*)d_in[4];
  const float* kv_norm_w= (const float*)d_in[5];
  const float* w_kv_up  = (const float*)d_in[6];
  const float* w_o      = (const float*)d_in[7];
  float* outp = (float*)d_out;

  char* ws = (char*)d_ws;
  size_t off = 0;
  auto alloc = [&](size_t bytes) {
    void* p = ws + off;
    off += (bytes + 255) & ~(size_t)255;
    return p;
  };
  unsigned short* x_bf     = (unsigned short*)alloc((size_t)TT * DIM * 2);   // reused: attn_bf
  unsigned short* wdown_bf = (unsigned short*)alloc((size_t)WDN * DIM * 2);
  unsigned short* wqu_bf   = (unsigned short*)alloc((size_t)QD * Q_RANK * 2);
  unsigned short* wkvu_bf  = (unsigned short*)alloc((size_t)KVUP_D * KV_RANK * 2);
  unsigned short* wo_bf    = (unsigned short*)alloc((size_t)DIM * DIM * 2);
  unsigned short* cqkv_bf  = (unsigned short*)alloc((size_t)TT * WDN * 2);
  unsigned short* cq_bf    = (unsigned short*)alloc((size_t)TT * Q_RANK * 2);
  unsigned short* ckv_bf   = (unsigned short*)alloc((size_t)TT * KV_RANK * 2);
  unsigned short* qb_bf    = (unsigned short*)alloc((size_t)TT * QD * 2);
  unsigned short* kbuf     = (unsigned short*)alloc((size_t)NH * TT * QKH * 2);
  unsigned short* vtb      = (unsigned short*)alloc((size_t)NH * VD * TT * 2);
  unsigned short* Opart    = (unsigned short*)alloc((size_t)1024 * 128 * 128 * 2);
  float*          mlbuf    = (float*)alloc((size_t)1024 * 128 * 2 * 4);
  unsigned short* attn_bf  = x_bf;  // x_bf dead after down-GEMM

  {
    int total = TT * DIM / 4 + WDN * 2048 / 4 + QD * Q_RANK / 4 +
                KVUP_D * KV_RANK / 4 + DIM * DIM / 4;
    convert_all<<<dim3((total + 255) / 256), dim3(256), 0, stream>>>(
        x, w_q_down, w_kv_down, w_q_up, w_kv_up, w_o,
        x_bf, wdown_bf, wqu_bf, wkvu_bf, wo_bf);
  }

  dim3 blk(256);
  // combined down-proj: cqkv = x @ [w_q_down; w_kv_down; pad]^T  [2048 x 2176]
  gemm_m64<<<dim3(WDN / 128, TT / 64), blk, 0, stream>>>(
      x_bf, wdown_bf, nullptr, cqkv_bf, DIM, DIM, DIM, WDN);
  rmsnorm_both<<<dim3(TT), blk, 0, stream>>>(cqkv_bf, q_norm_w, kv_norm_w, cq_bf, ckv_bf);
  // qup -> qb ; kvup -> kbuf (k_nope) + vtb (V^T), one dispatch (single-buf core)
  gemm_dual<<<dim3(896), blk, 0, stream>>>(cq_bf, wqu_bf, qb_bf,
                                           ckv_bf, wkvu_bf, kbuf, vtb);
  rope_kernel<<<dim3(TT), blk, 0, stream>>>(qb_bf, cqkv_bf, kbuf);
  attn_part<<<dim3(640), blk, 0, stream>>>(qb_bf, kbuf, vtb, Opart, mlbuf);
  attn_combine<<<dim3(512), blk, 0, stream>>>(Opart, mlbuf, attn_bf);
  // out = attn @ w_o^T  [2048 x 2048]
  gemm_m64<<<dim3(DIM / 128, TT / 64), blk, 0, stream>>>(
      attn_bf, wo_bf, outp, nullptr, DIM, DIM, DIM, DIM);
}

// Round 18
// 205.421 us; speedup vs baseline: 1.2173x; 1.1382x over previous
//
#include <hip/hip_runtime.h>
#include <hip/hip_bf16.h>

typedef short short8 __attribute__((ext_vector_type(8)));
typedef float f32x4 __attribute__((ext_vector_type(4)));

#define DIM 2048
#define NH 16
#define KV_RANK 512
#define Q_RANK 1536
#define ROPE_D 64
#define NOPE 128
#define VD 128
#define TT 2048
#define QKH 192                   // NOPE + ROPE
#define QD (NH * QKH)             // 3072
#define KVUP_D (NH * (NOPE + VD)) // 4096
#define WDN 2176                  // padded combined down-proj N (1536 + 576 + 64 pad)

__device__ inline unsigned short f2bf(float f) {
  __hip_bfloat16 h = __float2bfloat16(f);
  union { __hip_bfloat16 h; unsigned short u; } cv; cv.h = h; return cv.u;
}
__device__ inline float bf2f(unsigned short u) {
  union { unsigned int i; float f; } cv; cv.i = ((unsigned int)u) << 16; return cv.f;
}
__device__ inline void gload_lds16(const void* g, void* l) {
  __builtin_amdgcn_global_load_lds(
      (const __attribute__((address_space(1))) void*)g,
      (__attribute__((address_space(3))) void*)l, 16, 0, 0);
}

// ---------------- all fp32 -> bf16 converts in one launch ----------------
__global__ __launch_bounds__(256) void convert_all(
    const float* __restrict__ x, const float* __restrict__ wqd,
    const float* __restrict__ wkvd, const float* __restrict__ wqu,
    const float* __restrict__ wkvu, const float* __restrict__ wo,
    unsigned short* __restrict__ xb, unsigned short* __restrict__ wdb,
    unsigned short* __restrict__ wqub, unsigned short* __restrict__ wkvub,
    unsigned short* __restrict__ wob) {
  int i = blockIdx.x * 256 + threadIdx.x;
  const int n0 = TT * DIM / 4;
  const int n1 = WDN * 2048 / 4;
  const int n2 = QD * Q_RANK / 4;
  const int n3 = KVUP_D * KV_RANK / 4;
  const int n4 = DIM * DIM / 4;
  float4 v;
  unsigned short* dst;
  if (i < n0) { v = reinterpret_cast<const float4*>(x)[i]; dst = xb; }
  else if ((i -= n0) < n1) {
    int row = i >> 9, c4 = i & 511;   // 512 float4 per 2048-col row
    if (row < 1536)      v = reinterpret_cast<const float4*>(wqd)[row * 512 + c4];
    else if (row < 2112) v = reinterpret_cast<const float4*>(wkvd)[(row - 1536) * 512 + c4];
    else                 v = make_float4(0.f, 0.f, 0.f, 0.f);
    dst = wdb;
  }
  else if ((i -= n1) < n2) { v = reinterpret_cast<const float4*>(wqu)[i]; dst = wqub; }
  else if ((i -= n2) < n3) { v = reinterpret_cast<const float4*>(wkvu)[i]; dst = wkvub; }
  else if ((i -= n3) < n4) { v = reinterpret_cast<const float4*>(wo)[i]; dst = wob; }
  else return;
  ushort4 o;
  o.x = f2bf(v.x); o.y = f2bf(v.y); o.z = f2bf(v.z); o.w = f2bf(v.w);
  reinterpret_cast<ushort4*>(dst)[i] = o;
}

// ------- single-buffered m97-style core, 128M x 128N (for gemm_dual) -------
__device__ __forceinline__ void gemm_core_sb(const unsigned short* __restrict__ A,
                                             const unsigned short* __restrict__ W,
                                             unsigned short* As, unsigned short* Bs,
                                             int K, int lda, int ldb,
                                             int bm, int bn, int tid,
                                             f32x4 (&acc)[4][4]) {
  const int lane = tid & 63, wave = tid >> 6;
  const int wm = (wave >> 1) * 64, wn = (wave & 1) * 64;
  const int fr = lane & 15, fg = lane >> 4;
  const int sr = lane >> 3, scb = (lane & 7) ^ sr;
  const int r0 = wave * 32;

  const unsigned short* Ag = A + (size_t)(bm + r0 + sr) * lda + scb * 8;
  const unsigned short* Wg = W + (size_t)(bn + r0 + sr) * ldb + scb * 8;

  for (int k0 = 0; k0 < K; k0 += 64) {
#pragma unroll
    for (int i = 0; i < 4; ++i) {
      gload_lds16(Ag + k0 + (size_t)(i * 8) * lda, As + r0 * 64 + i * 512);
      gload_lds16(Wg + k0 + (size_t)(i * 8) * ldb, Bs + r0 * 64 + i * 512);
    }
    __syncthreads();
    __builtin_amdgcn_s_setprio(1);
#pragma unroll
    for (int kk = 0; kk < 2; ++kk) {
      short8 a[4], b[4];
#pragma unroll
      for (int i = 0; i < 4; ++i) {
        int ra = wm + i * 16 + fr;
        a[i] = *reinterpret_cast<const short8*>(&As[ra * 64 + (((kk * 4 + fg) ^ (ra & 7)) * 8)]);
        int rb = wn + i * 16 + fr;
        b[i] = *reinterpret_cast<const short8*>(&Bs[rb * 64 + (((kk * 4 + fg) ^ (rb & 7)) * 8)]);
      }
#pragma unroll
      for (int i = 0; i < 4; ++i)
#pragma unroll
        for (int j = 0; j < 4; ++j)
          acc[i][j] = __builtin_amdgcn_mfma_f32_16x16x32_bf16(a[i], b[j], acc[i][j], 0, 0, 0);
    }
    __builtin_amdgcn_s_setprio(0);
    __syncthreads();
  }
}

// ------- 64M x 128N single-buffered GEMM (2+ blocks/CU for ~1-block/CU grids) --
// grid = (N/128, M/64), block = 256 (4 waves, each 32x64). LDS 24KB.
__global__ __launch_bounds__(256) void gemm_m64(const unsigned short* __restrict__ A,
                                                const unsigned short* __restrict__ W,
                                                float* __restrict__ Cf,
                                                unsigned short* __restrict__ Cb,
                                                int K, int lda, int ldb, int ldc) {
  __shared__ __align__(16) unsigned short As[64 * 64];    // 8KB
  __shared__ __align__(16) unsigned short Bs[128 * 64];   // 16KB
  const int tid = threadIdx.x;
  const int bm = blockIdx.y * 64, bn = blockIdx.x * 128;
  const int lane = tid & 63, wave = tid >> 6;
  const int wm = (wave >> 1) * 32, wn = (wave & 1) * 64;
  const int fr = lane & 15, fg = lane >> 4;

  f32x4 acc[2][4] = {};

  for (int k0 = 0; k0 < K; k0 += 64) {
    // stage A: 512 units (2/thread), dest linear, source col-block XOR row
#pragma unroll
    for (int i = 0; i < 2; ++i) {
      int u = tid + i * 256;
      int row = u >> 3, cb = u & 7;
      gload_lds16(A + (size_t)(bm + row) * lda + k0 + ((cb ^ (row & 7)) * 8), As + u * 8);
    }
    // stage B: 1024 units (4/thread)
#pragma unroll
    for (int i = 0; i < 4; ++i) {
      int u = tid + i * 256;
      int row = u >> 3, cb = u & 7;
      gload_lds16(W + (size_t)(bn + row) * ldb + k0 + ((cb ^ (row & 7)) * 8), Bs + u * 8);
    }
    __syncthreads();
    __builtin_amdgcn_s_setprio(1);
#pragma unroll
    for (int kk = 0; kk < 2; ++kk) {
      short8 a[2], b[4];
#pragma unroll
      for (int i = 0; i < 2; ++i) {
        int ra = wm + i * 16 + fr;
        a[i] = *reinterpret_cast<const short8*>(&As[ra * 64 + (((kk * 4 + fg) ^ (ra & 7)) * 8)]);
      }
#pragma unroll
      for (int j = 0; j < 4; ++j) {
        int rb = wn + j * 16 + fr;
        b[j] = *reinterpret_cast<const short8*>(&Bs[rb * 64 + (((kk * 4 + fg) ^ (rb & 7)) * 8)]);
      }
#pragma unroll
      for (int i = 0; i < 2; ++i)
#pragma unroll
        for (int j = 0; j < 4; ++j)
          acc[i][j] = __builtin_amdgcn_mfma_f32_16x16x32_bf16(a[i], b[j], acc[i][j], 0, 0, 0);
    }
    __builtin_amdgcn_s_setprio(0);
    __syncthreads();
  }

  if (Cb) {
#pragma unroll
    for (int i = 0; i < 2; ++i) {
      int row0 = bm + wm + i * 16 + fg * 4;
#pragma unroll
      for (int j = 0; j < 4; ++j) {
        int col = bn + wn + j * 16 + fr;
#pragma unroll
        for (int r = 0; r < 4; ++r)
          Cb[(size_t)(row0 + r) * ldc + col] = f2bf(acc[i][j][r]);
      }
    }
  } else {
#pragma unroll
    for (int i = 0; i < 2; ++i) {
      int row0 = bm + wm + i * 16 + fg * 4;
#pragma unroll
      for (int j = 0; j < 4; ++j) {
        int col = bn + wn + j * 16 + fr;
#pragma unroll
        for (int r = 0; r < 4; ++r)
          Cf[(size_t)(row0 + r) * ldc + col] = acc[i][j][r];
      }
    }
  }
}

// ------- dual GEMM (single-buf core): bx<384 qup -> C1; else kvup -> kbuf+vtb --
__global__ __launch_bounds__(256) void gemm_dual(
    const unsigned short* __restrict__ A1, const unsigned short* __restrict__ W1,
    unsigned short* __restrict__ C1,
    const unsigned short* __restrict__ A2, const unsigned short* __restrict__ W2,
    unsigned short* __restrict__ kbuf, unsigned short* __restrict__ vt) {
  __shared__ __align__(16) unsigned short As[128 * 64];
  __shared__ __align__(16) unsigned short Bs[128 * 64];
  const int tid = threadIdx.x;
  const int s = blockIdx.x;
  const unsigned short *A, *W;
  int K, lda, bm, bn;
  const bool isq = (s < 384);
  if (isq) {
    A = A1; W = W1; K = Q_RANK; lda = Q_RANK;
    bn = (s % 24) * 128; bm = (s / 24) * 128;
  } else {
    int b2 = s - 384;
    A = A2; W = W2; K = KV_RANK; lda = KV_RANK;
    bn = (b2 & 31) * 128; bm = (b2 >> 5) * 128;
  }
  const int lane = tid & 63, wave = tid >> 6;
  const int wm = (wave >> 1) * 64, wn = (wave & 1) * 64;
  const int fr = lane & 15, fg = lane >> 4;

  f32x4 acc[4][4] = {};
  gemm_core_sb(A, W, As, Bs, K, lda, lda, bm, bn, tid, acc);

  if (isq) {
#pragma unroll
    for (int i = 0; i < 4; ++i) {
      int row0 = bm + wm + i * 16 + fg * 4;
#pragma unroll
      for (int j = 0; j < 4; ++j) {
        int col = bn + wn + j * 16 + fr;
#pragma unroll
        for (int r = 0; r < 4; ++r)
          C1[(size_t)(row0 + r) * QD + col] = f2bf(acc[i][j][r]);
      }
    }
  } else {
    // kvup: cols [h*256, h*256+128) = k_nope -> kbuf[h][t][c]; [128,256) = v -> vt
#pragma unroll
    for (int i = 0; i < 4; ++i) {
      int row0 = bm + wm + i * 16 + fg * 4;
#pragma unroll
      for (int j = 0; j < 4; ++j) {
        int col = bn + wn + j * 16 + fr;
        int hh = col >> 8, cc = col & 255;
        if (cc < 128) {
#pragma unroll
          for (int r = 0; r < 4; ++r)
            kbuf[((size_t)hh * TT + row0 + r) * QKH + cc] = f2bf(acc[i][j][r]);
        } else {
          ushort4 w4;
          w4.x = f2bf(acc[i][j][0]); w4.y = f2bf(acc[i][j][1]);
          w4.z = f2bf(acc[i][j][2]); w4.w = f2bf(acc[i][j][3]);
          *reinterpret_cast<ushort4*>(vt + (size_t)(hh * VD + cc - 128) * TT + row0) = w4;
        }
      }
    }
  }
}

// ------- merged RMSNorm: per row, q-norm (1536) + kv-norm (512) -------
__global__ __launch_bounds__(256) void rmsnorm_both(
    const unsigned short* __restrict__ cqkv,
    const float* __restrict__ qw, const float* __restrict__ kvw,
    unsigned short* __restrict__ cq, unsigned short* __restrict__ ckv) {
  const int row = blockIdx.x, tid = threadIdx.x;
  __shared__ float red[256];
  const unsigned short* base = cqkv + (size_t)row * WDN;

#pragma unroll
  for (int ph = 0; ph < 2; ++ph) {
    const int cols = ph ? KV_RANK : Q_RANK;
    const int nch = cols >> 3;
    const unsigned short* x = base + (ph ? Q_RANK : 0);
    const float* w = ph ? kvw : qw;
    unsigned short* out = (ph ? ckv : cq) + (size_t)row * cols;
    float ss = 0.f;
    for (int cb = tid; cb < nch; cb += 256) {
      short8 v = *reinterpret_cast<const short8*>(x + cb * 8);
#pragma unroll
      for (int e = 0; e < 8; ++e) { float f = bf2f((unsigned short)v[e]); ss += f * f; }
    }
    red[tid] = ss; __syncthreads();
    for (int off = 128; off > 0; off >>= 1) {
      if (tid < off) red[tid] += red[tid + off];
      __syncthreads();
    }
    float r = rsqrtf(red[0] / (float)cols + 1e-6f);
    __syncthreads();
    for (int cb = tid; cb < nch; cb += 256) {
      short8 v = *reinterpret_cast<const short8*>(x + cb * 8);
      ushort4 o0, o1;
      o0.x = f2bf(bf2f((unsigned short)v[0]) * r * w[cb * 8 + 0]);
      o0.y = f2bf(bf2f((unsigned short)v[1]) * r * w[cb * 8 + 1]);
      o0.z = f2bf(bf2f((unsigned short)v[2]) * r * w[cb * 8 + 2]);
      o0.w = f2bf(bf2f((unsigned short)v[3]) * r * w[cb * 8 + 3]);
      o1.x = f2bf(bf2f((unsigned short)v[4]) * r * w[cb * 8 + 4]);
      o1.y = f2bf(bf2f((unsigned short)v[5]) * r * w[cb * 8 + 5]);
      o1.z = f2bf(bf2f((unsigned short)v[6]) * r * w[cb * 8 + 6]);
      o1.w = f2bf(bf2f((unsigned short)v[7]) * r * w[cb * 8 + 7]);
      *reinterpret_cast<ushort4*>(out + cb * 8) = o0;
      *reinterpret_cast<ushort4*>(out + cb * 8 + 4) = o1;
    }
  }
}

// ------- RoPE in-place on bf16 q rows + k_rope into kbuf (all heads) -------
__global__ __launch_bounds__(256) void rope_kernel(unsigned short* __restrict__ qb,
                                                   const unsigned short* __restrict__ cqkv,
                                                   unsigned short* __restrict__ kbuf) {
  const int t = blockIdx.x, tid = threadIdx.x;
  unsigned short* qrow = qb + (size_t)t * QD;
  for (int p = tid; p < NH * 32 + 32; p += 256) {
    int j = (p < NH * 32) ? (p & 31) : (p - NH * 32);
    float inv = powf(500000.0f, -(float)(2 * j) * (1.0f / 64.0f));
    float ang = (float)t * inv;
    float sv, cv;
    sincosf(ang, &sv, &cv);
    if (p < NH * 32) {
      int h = p >> 5;
      unsigned short* b = qrow + h * QKH + NOPE + 2 * j;
      float e = bf2f(b[0]), o = bf2f(b[1]);
      b[0] = f2bf(e * cv - o * sv);
      b[1] = f2bf(o * cv + e * sv);
    } else {
      const unsigned short* b = cqkv + (size_t)t * WDN + 2048 + 2 * j;
      float e = bf2f(b[0]), o = bf2f(b[1]);
      unsigned short re = f2bf(e * cv - o * sv);
      unsigned short ro = f2bf(o * cv + e * sv);
#pragma unroll
      for (int hh = 0; hh < NH; ++hh) {
        kbuf[((size_t)hh * TT + t) * QKH + NOPE + 2 * j]     = re;
        kbuf[((size_t)hh * TT + t) * QKH + NOPE + 2 * j + 1] = ro;
      }
    }
  }
}

// ---- k-split MFMA flash attention (r14: split-wait + hoisted PV) ----
// 640 blocks: b -> h = b&15, w = b>>4 (big q-tiles first). qt 0..15 (128 q-rows),
// chunk c covers 64-key k-tiles [8c, min(8c+8, 2qt+2)).
__global__ __launch_bounds__(256, 2) void attn_part(
    const unsigned short* __restrict__ qb,    // [T][3072] (rope applied)
    const unsigned short* __restrict__ kbuf,  // [H][T][192]
    const unsigned short* __restrict__ vtb,   // [H*128][T]
    unsigned short* __restrict__ Opart,       // [1024 slots][128][128] bf16
    float* __restrict__ ml)                   // [1024 slots][128][2]
{
  const int b = blockIdx.x;
  const int h = b & 15;
  const int w = b >> 4;
  int qt, c;
  if (w < 16)      { qt = 15 - (w >> 2); c = w & 3; }
  else if (w < 28) { int v = w - 16; qt = 11 - v / 3; c = v % 3; }
  else if (w < 36) { qt = 7 - ((w - 28) >> 1); c = (w - 28) & 1; }
  else             { qt = 3 - (w - 36); c = 0; }
  const int t0 = qt * 128;
  const int ktlo = c * 8;
  const int kthi = min(c * 8 + 8, 2 * qt + 2);
  const int tid = threadIdx.x;
  const int lane = tid & 63, wv = tid >> 6;
  const int fr = lane & 15, fg = lane >> 4;

  __shared__ __align__(16) unsigned short KVl[2560 * 8];     // K 1536u + V 1024u = 40KB
  __shared__ __align__(16) unsigned short Ps[4][2][16 * 64]; // 16KB (both subtiles)
  unsigned short* Kl = KVl;             // [64][192] + XOR
  unsigned short* Vt = KVl + 12288;     // [128][64] + XOR

  short8 qf[2][6];
#pragma unroll
  for (int s = 0; s < 2; ++s) {
    const unsigned short* qrow = qb + (size_t)(t0 + wv * 32 + s * 16 + fr) * QD + h * QKH;
#pragma unroll
    for (int kc = 0; kc < 6; ++kc)
      qf[s][kc] = *reinterpret_cast<const short8*>(qrow + kc * 32 + fg * 8);
  }
  asm volatile("s_waitcnt vmcnt(0)" ::: "memory");  // drain Q so loop vmcnt counts are exact

  f32x4 o[2][8] = {};
  float m2[2] = {-1e30f, -1e30f};
  float l2[2] = {0.f, 0.f};
  const float scale = 0.0721687836487032f;  // 1/sqrt(192)
  const unsigned short* kb = kbuf + (size_t)h * TT * QKH;
  const unsigned short* vb = vtb + (size_t)h * VD * TT;

  for (int kt = ktlo; kt < kthi; ++kt) {
    const int kt0 = kt * 64;
    // stage K (6 gloads/thread), then V (4 gloads/thread)
#pragma unroll
    for (int i = 0; i < 6; ++i) {
      int u = tid + i * 256;
      int row = u / 24, cb = u - (u / 24) * 24;
      int cbs = cb ^ (row & 7);
      gload_lds16(kb + (size_t)(kt0 + row) * QKH + cbs * 8, Kl + u * 8);
    }
#pragma unroll
    for (int i = 0; i < 4; ++i) {
      int u = tid + i * 256;
      int d = u >> 3, cb = u & 7;
      int cbs = cb ^ (d & 7);
      gload_lds16(vb + (size_t)d * TT + kt0 + cbs * 8, Vt + u * 8);
    }
    asm volatile("s_waitcnt vmcnt(4)" ::: "memory");  // K landed; V's 4 still in flight
    __builtin_amdgcn_s_barrier();
    asm volatile("" ::: "memory");

    // S^T = K Q : uses Kl only (V still arriving)
    f32x4 sA[2][4] = {};
    __builtin_amdgcn_s_setprio(1);
#pragma unroll
    for (int kc = 0; kc < 6; ++kc) {
#pragma unroll
      for (int kr = 0; kr < 4; ++kr) {
        int row = kr * 16 + fr;
        short8 kf = *reinterpret_cast<const short8*>(
            &Kl[row * QKH + (((kc * 4 + fg) ^ (row & 7)) * 8)]);
        sA[0][kr] = __builtin_amdgcn_mfma_f32_16x16x32_bf16(kf, qf[0][kc], sA[0][kr], 0, 0, 0);
        sA[1][kr] = __builtin_amdgcn_mfma_f32_16x16x32_bf16(kf, qf[1][kc], sA[1][kr], 0, 0, 0);
      }
    }
    __builtin_amdgcn_s_setprio(0);

    const bool diag = (kt0 + 64 > t0);
#pragma unroll
    for (int s = 0; s < 2; ++s) {
      const int qg = t0 + wv * 32 + s * 16 + fr;
      float mx = -1e30f;
#pragma unroll
      for (int kr = 0; kr < 4; ++kr)
#pragma unroll
        for (int r = 0; r < 4; ++r) {
          float svv = sA[s][kr][r] * scale;
          if (diag && (kt0 + kr * 16 + fg * 4 + r) > qg) svv = -1e30f;
          sA[s][kr][r] = svv;
          mx = fmaxf(mx, svv);
        }
      mx = fmaxf(mx, __shfl_xor(mx, 16));
      mx = fmaxf(mx, __shfl_xor(mx, 32));
      float mn = fmaxf(m2[s], mx);
      float corr = __expf(m2[s] - mn);
      m2[s] = mn;
      float ssum = 0.f;
#pragma unroll
      for (int kr = 0; kr < 4; ++kr) {
        ushort4 pk;
        float p0 = __expf(sA[s][kr][0] - mn);
        float p1 = __expf(sA[s][kr][1] - mn);
        float p2 = __expf(sA[s][kr][2] - mn);
        float p3 = __expf(sA[s][kr][3] - mn);
        ssum += p0 + p1 + p2 + p3;
        pk.x = f2bf(p0); pk.y = f2bf(p1); pk.z = f2bf(p2); pk.w = f2bf(p3);
        // P[q=fr][k = kr*16 + fg*4 + r]; unit = kr*2 + (fg>>1), XOR row fr
        *reinterpret_cast<ushort4*>(
            &Ps[wv][s][fr * 64 + (((kr * 2 + (fg >> 1)) ^ (fr & 7)) * 8) + (fg & 1) * 4]) = pk;
      }
      ssum += __shfl_xor(ssum, 16);
      ssum += __shfl_xor(ssum, 32);
      l2[s] = l2[s] * corr + ssum;
      if (__any(corr != 1.0f)) {
        float c0 = __shfl(corr, fg * 4 + 0);
        float c1 = __shfl(corr, fg * 4 + 1);
        float c2 = __shfl(corr, fg * 4 + 2);
        float c3 = __shfl(corr, fg * 4 + 3);
#pragma unroll
        for (int dj = 0; dj < 8; ++dj) {
          o[s][dj][0] *= c0; o[s][dj][1] *= c1;
          o[s][dj][2] *= c2; o[s][dj][3] *= c3;
        }
      }
    }

    // V now needed: wait remaining gloads, barrier, then PV (hoisted over s)
    asm volatile("s_waitcnt vmcnt(0)" ::: "memory");
    __builtin_amdgcn_s_barrier();
    asm volatile("" ::: "memory");

    __builtin_amdgcn_s_setprio(1);
#pragma unroll
    for (int kk = 0; kk < 2; ++kk) {
      short8 pa0 = *reinterpret_cast<const short8*>(
          &Ps[wv][0][fr * 64 + (((kk * 4 + fg) ^ (fr & 7)) * 8)]);
      short8 pa1 = *reinterpret_cast<const short8*>(
          &Ps[wv][1][fr * 64 + (((kk * 4 + fg) ^ (fr & 7)) * 8)]);
#pragma unroll
      for (int dj = 0; dj < 8; ++dj) {
        int dv = dj * 16 + fr;
        short8 bv = *reinterpret_cast<const short8*>(
            &Vt[dv * 64 + (((kk * 4 + fg) ^ (dv & 7)) * 8)]);
        o[0][dj] = __builtin_amdgcn_mfma_f32_16x16x32_bf16(pa0, bv, o[0][dj], 0, 0, 0);
        o[1][dj] = __builtin_amdgcn_mfma_f32_16x16x32_bf16(pa1, bv, o[1][dj], 0, 0, 0);
      }
    }
    __builtin_amdgcn_s_setprio(0);
    asm volatile("" ::: "memory");
    __builtin_amdgcn_s_barrier();   // protect Kl/Vt/Ps before next-iter staging
  }

  const int slot = (h * 16 + qt) * 4 + c;
#pragma unroll
  for (int s = 0; s < 2; ++s) {
#pragma unroll
    for (int r = 0; r < 4; ++r) {
      int row = wv * 32 + s * 16 + fg * 4 + r;
      unsigned short* orow = Opart + ((size_t)slot * 128 + row) * 128;
#pragma unroll
      for (int dj = 0; dj < 8; ++dj)
        orow[dj * 16 + fr] = f2bf(o[s][dj][r]);
    }
    if (fg == 0) {
      int row = wv * 32 + s * 16 + fr;
      ml[((size_t)slot * 128 + row) * 2]     = m2[s];
      ml[((size_t)slot * 128 + row) * 2 + 1] = l2[s];
    }
  }
}

// ---------------- combine partials -> attn output (bf16) ----------------
__global__ __launch_bounds__(256) void attn_combine(
    const unsigned short* __restrict__ Opart, const float* __restrict__ ml,
    unsigned short* __restrict__ out) {
  const int bid = blockIdx.x;          // h*32 + qt*2 + rowhalf
  const int h = bid >> 5;
  const int qt = (bid >> 1) & 15;
  const int rh = bid & 1;
  const int nch = qt / 4 + 1;
  const int tid = threadIdx.x;
  const int row = rh * 64 + (tid >> 2), dg = tid & 3;
  const int base = (h * 16 + qt) * 4;
  float mm[4], ll[4];
  float M = -1e30f;
#pragma unroll
  for (int cc = 0; cc < 4; ++cc) {
    if (cc < nch) {
      mm[cc] = ml[((size_t)(base + cc) * 128 + row) * 2];
      ll[cc] = ml[((size_t)(base + cc) * 128 + row) * 2 + 1];
      M = fmaxf(M, mm[cc]);
    } else { mm[cc] = -1e30f; ll[cc] = 0.f; }
  }
  float L = 0.f;
#pragma unroll
  for (int cc = 0; cc < 4; ++cc) {
    mm[cc] = __expf(mm[cc] - M);
    L += ll[cc] * mm[cc];
  }
  float acc[32] = {};
#pragma unroll
  for (int cc = 0; cc < 4; ++cc) {
    if (cc < nch) {
      const unsigned short* op = Opart + ((size_t)(base + cc) * 128 + row) * 128 + dg * 32;
      float sc = mm[cc];
#pragma unroll
      for (int e8 = 0; e8 < 4; ++e8) {
        short8 v = *reinterpret_cast<const short8*>(op + e8 * 8);
#pragma unroll
        for (int e = 0; e < 8; ++e) acc[e8 * 8 + e] += bf2f((unsigned short)v[e]) * sc;
      }
    }
  }
  float linv = 1.0f / L;
  unsigned short* dst = out + (size_t)(qt * 128 + row) * DIM + h * VD + dg * 32;
#pragma unroll
  for (int e4 = 0; e4 < 8; ++e4) {
    ushort4 w4;
    w4.x = f2bf(acc[e4 * 4 + 0] * linv);
    w4.y = f2bf(acc[e4 * 4 + 1] * linv);
    w4.z = f2bf(acc[e4 * 4 + 2] * linv);
    w4.w = f2bf(acc[e4 * 4 + 3] * linv);
    *reinterpret_cast<ushort4*>(dst + e4 * 4) = w4;
  }
}

// ---------------- launch ----------------
extern "C" void kernel_launch(void* const* d_in, const int* in_sizes, int n_in,
                              void* d_out, int out_size, void* d_ws, size_t ws_size,
                              hipStream_t stream) {
  const float* x        = (const float*)d_in[0];
  const float* w_q_down = (const float*)d_in[1];
  const float* q_norm_w = (const float*)d_in[2];
  const float* w_q_up   = (const float*)d_in[3];
  const float* w_kv_down= (const float*)d_in[4];
  const float* kv_norm_w= (const float*)d_in[5];
  const float* w_kv_up  = (const float*)d_in[6];
  const float* w_o      = (const float*)d_in[7];
  float* outp = (float*)d_out;

  char* ws = (char*)d_ws;
  size_t off = 0;
  auto alloc = [&](size_t bytes) {
    void* p = ws + off;
    off += (bytes + 255) & ~(size_t)255;
    return p;
  };
  unsigned short* x_bf     = (unsigned short*)alloc((size_t)TT * DIM * 2);   // reused: attn_bf
  unsigned short* wdown_bf = (unsigned short*)alloc((size_t)WDN * DIM * 2);
  unsigned short* wqu_bf   = (unsigned short*)alloc((size_t)QD * Q_RANK * 2);
  unsigned short* wkvu_bf  = (unsigned short*)alloc((size_t)KVUP_D * KV_RANK * 2);
  unsigned short* wo_bf    = (unsigned short*)alloc((size_t)DIM * DIM * 2);
  unsigned short* cqkv_bf  = (unsigned short*)alloc((size_t)TT * WDN * 2);
  unsigned short* cq_bf    = (unsigned short*)alloc((size_t)TT * Q_RANK * 2);
  unsigned short* ckv_bf   = (unsigned short*)alloc((size_t)TT * KV_RANK * 2);
  unsigned short* qb_bf    = (unsigned short*)alloc((size_t)TT * QD * 2);
  unsigned short* kbuf     = (unsigned short*)alloc((size_t)NH * TT * QKH * 2);
  unsigned short* vtb      = (unsigned short*)alloc((size_t)NH * VD * TT * 2);
  unsigned short* Opart    = (unsigned short*)alloc((size_t)1024 * 128 * 128 * 2);
  float*          mlbuf    = (float*)alloc((size_t)1024 * 128 * 2 * 4);
  unsigned short* attn_bf  = x_bf;  // x_bf dead after down-GEMM

  {
    int total = TT * DIM / 4 + WDN * 2048 / 4 + QD * Q_RANK / 4 +
                KVUP_D * KV_RANK / 4 + DIM * DIM / 4;
    convert_all<<<dim3((total + 255) / 256), dim3(256), 0, stream>>>(
        x, w_q_down, w_kv_down, w_q_up, w_kv_up, w_o,
        x_bf, wdown_bf, wqu_bf, wkvu_bf, wo_bf);
  }

  dim3 blk(256);
  // combined down-proj: cqkv = x @ [w_q_down; w_kv_down; pad]^T  [2048 x 2176]
  gemm_m64<<<dim3(WDN / 128, TT / 64), blk, 0, stream>>>(
      x_bf, wdown_bf, nullptr, cqkv_bf, DIM, DIM, DIM, WDN);
  rmsnorm_both<<<dim3(TT), blk, 0, stream>>>(cqkv_bf, q_norm_w, kv_norm_w, cq_bf, ckv_bf);
  // qup -> qb ; kvup -> kbuf (k_nope) + vtb (V^T), one dispatch (single-buf core)
  gemm_dual<<<dim3(896), blk, 0, stream>>>(cq_bf, wqu_bf, qb_bf,
                                           ckv_bf, wkvu_bf, kbuf, vtb);
  rope_kernel<<<dim3(TT), blk, 0, stream>>>(qb_bf, cqkv_bf, kbuf);
  attn_part<<<dim3(640), blk, 0, stream>>>(qb_bf, kbuf, vtb, Opart, mlbuf);
  attn_combine<<<dim3(512), blk, 0, stream>>>(Opart, mlbuf, attn_bf);
  // out = attn @ w_o^T  [2048 x 2048]
  gemm_m64<<<dim3(DIM / 128, TT / 64), blk, 0, stream>>>(
      attn_bf, wo_bf, outp, nullptr, DIM, DIM, DIM, DIM);
}